// Round 13
// baseline (283.049 us; speedup 1.0000x reference)
//
#include <hip/hip_runtime.h>
#include <hip/hip_bf16.h>

// CHNN=1024, K=L=2048. Inputs fp32, output fp32. bf16 MFMA (16x16x32), fp32
// acc, TN layout. Round 13: (1) NO LDS in GEMMs -- single-wave blocks share
// nothing, so fragments load straight global->VGPR (bf16x8 = dwordx4; TN makes
// them lane-contiguous), register-double-buffered 2 K-steps deep. Kills the
// 8-way LDS bank conflict of the DMA layout and the DMA itself. (2) XCD patch
// swizzle (bid&7 -> xcd, compact pm x pn patch per XCD, working set <= 4MB) so
// tile re-reads (~1.4 GB total) hit XCD-local L2 (34.5 TB/s) instead of L3.
// Dataflow unchanged from r11/r12: 7 launches, vmm-associativity trick.

typedef __bf16 bf16x4 __attribute__((ext_vector_type(4)));
typedef __bf16 bf16x8 __attribute__((ext_vector_type(8)));
typedef float  f32x4  __attribute__((ext_vector_type(4)));

// PM/PN: per-XCD patch dims in 64-tiles; NPC: patch-grid columns (8/NPC rows).
template<typename OT, int BIAS_, bool RELU_, int STORE_, int PM_, int PN_, int NPC_>
struct GC {
    using OUT_T = OT;
    static constexpr int BIAS = BIAS_, STORE = STORE_;
    static constexpr bool RELU = RELU_;
    static constexpr int PM = PM_, PN = PN_, NPC = NPC_;
};

// Single-wave 64x64 TN GEMM. C(M,N) = A(M,K)*B(N,K)^T (+bias, relu).
// BIAS: 0 none, 1 row, 2 col. STORE: 0 C[m][n], 1 CT[n][m] (16B over m).
template<class CF>
__device__ __forceinline__ void gemm_body(
    int bid,
    const __bf16* __restrict__ A, const __bf16* __restrict__ B,
    const float* __restrict__ bias,
    typename CF::OUT_T* __restrict__ C, typename CF::OUT_T* __restrict__ CT,
    int M, int N, int K)
{
    const int lane = threadIdx.x & 63;
    // XCD patch swizzle: xcd = bid&7 (round-robin dispatch heuristic).
    const int xcd = bid & 7, j = bid >> 3;
    const int pr = xcd / CF::NPC, pc = xcd % CF::NPC;
    const int jm = j / CF::PN, jn = j % CF::PN;
    const int m0 = (pr * CF::PM + jm) * 64;
    const int n0 = (pc * CF::PN + jn) * 64;

    // Per-lane fragment bases: row = x*16 + (lane&15), k-offset (lane>>4)*8.
    const __bf16* pA = A + (size_t)(m0 + (lane & 15)) * K + (lane >> 4) * 8;
    const __bf16* pB = B + (size_t)(n0 + (lane & 15)) * K + (lane >> 4) * 8;

    f32x4 acc[4][4];
    #pragma unroll
    for (int i = 0; i < 4; ++i)
        #pragma unroll
        for (int jj = 0; jj < 4; ++jj)
            acc[i][jj] = (f32x4){0.f, 0.f, 0.f, 0.f};

    bf16x8 a0[4], b0[4], a1[4], b1[4];
    #pragma unroll
    for (int i = 0; i < 4; ++i) {
        a0[i] = *(const bf16x8*)(pA + (size_t)(i * 16) * K);
        b0[i] = *(const bf16x8*)(pB + (size_t)(i * 16) * K);
        a1[i] = *(const bf16x8*)(pA + (size_t)(i * 16) * K + 32);
        b1[i] = *(const bf16x8*)(pB + (size_t)(i * 16) * K + 32);
    }

    for (int k0 = 0; k0 < K - 64; k0 += 64) {
        #pragma unroll
        for (int i = 0; i < 4; ++i)
            #pragma unroll
            for (int jj = 0; jj < 4; ++jj)
                acc[i][jj] = __builtin_amdgcn_mfma_f32_16x16x32_bf16(a0[i], b0[jj], acc[i][jj], 0, 0, 0);
        #pragma unroll
        for (int i = 0; i < 4; ++i) {
            a0[i] = *(const bf16x8*)(pA + (size_t)(i * 16) * K + k0 + 64);
            b0[i] = *(const bf16x8*)(pB + (size_t)(i * 16) * K + k0 + 64);
        }
        #pragma unroll
        for (int i = 0; i < 4; ++i)
            #pragma unroll
            for (int jj = 0; jj < 4; ++jj)
                acc[i][jj] = __builtin_amdgcn_mfma_f32_16x16x32_bf16(a1[i], b1[jj], acc[i][jj], 0, 0, 0);
        #pragma unroll
        for (int i = 0; i < 4; ++i) {
            a1[i] = *(const bf16x8*)(pA + (size_t)(i * 16) * K + k0 + 96);
            b1[i] = *(const bf16x8*)(pB + (size_t)(i * 16) * K + k0 + 96);
        }
    }
    // last two K-steps (loads already issued)
    #pragma unroll
    for (int i = 0; i < 4; ++i)
        #pragma unroll
        for (int jj = 0; jj < 4; ++jj)
            acc[i][jj] = __builtin_amdgcn_mfma_f32_16x16x32_bf16(a0[i], b0[jj], acc[i][jj], 0, 0, 0);
    #pragma unroll
    for (int i = 0; i < 4; ++i)
        #pragma unroll
        for (int jj = 0; jj < 4; ++jj)
            acc[i][jj] = __builtin_amdgcn_mfma_f32_16x16x32_bf16(a1[i], b1[jj], acc[i][jj], 0, 0, 0);

    // Epilogue. C/D layout: col=lane&15, row=(lane>>4)*4+reg (verified r6-r12).
    #pragma unroll
    for (int i = 0; i < 4; ++i) {
        const int rowb = m0 + i * 16 + (lane >> 4) * 4;
        #pragma unroll
        for (int jj = 0; jj < 4; ++jj) {
            const int col = n0 + jj * 16 + (lane & 15);
            f32x4 v = acc[i][jj];
            #pragma unroll
            for (int r = 0; r < 4; ++r) {
                float f = v[r];
                if (CF::BIAS == 1) f += bias[rowb + r];
                if (CF::BIAS == 2) f += bias[col];
                if (CF::RELU) f = fmaxf(f, 0.f);
                v[r] = f;
            }
            if (CF::STORE == 0) {
                #pragma unroll
                for (int r = 0; r < 4; ++r)
                    C[(size_t)(rowb + r) * N + col] = (typename CF::OUT_T)v[r];
            } else {
                if constexpr (sizeof(typename CF::OUT_T) == 4) {
                    *(f32x4*)&CT[(size_t)col * M + rowb] = v;
                } else {
                    bf16x4 w = { (__bf16)v[0], (__bf16)v[1], (__bf16)v[2], (__bf16)v[3] };
                    *(bf16x4*)&CT[(size_t)col * M + rowb] = w;
                }
            }
        }
    }
}

// Single-wave row softmax over 2048 bf16 (32 elems/lane, shuffle reduce).
__device__ __forceinline__ void softmax_row_w(__bf16* __restrict__ p)
{
    const int lane = threadIdx.x & 63;
    bf16x8 v[4];
    float f[32];
    #pragma unroll
    for (int r = 0; r < 4; ++r)
        v[r] = *(const bf16x8*)&p[(r * 64 + lane) * 8];
    float m = -1e30f;
    #pragma unroll
    for (int r = 0; r < 4; ++r)
        #pragma unroll
        for (int j = 0; j < 8; ++j) {
            f[r * 8 + j] = (float)v[r][j];
            m = fmaxf(m, f[r * 8 + j]);
        }
    #pragma unroll
    for (int s = 1; s < 64; s <<= 1) m = fmaxf(m, __shfl_xor(m, s, 64));
    float sum = 0.f;
    #pragma unroll
    for (int i = 0; i < 32; ++i) { f[i] = expf(f[i] - m); sum += f[i]; }
    #pragma unroll
    for (int s = 1; s < 64; s <<= 1) sum += __shfl_xor(sum, s, 64);
    const float inv = 1.f / sum;
    #pragma unroll
    for (int r = 0; r < 4; ++r) {
        bf16x8 w;
        #pragma unroll
        for (int j = 0; j < 8; ++j) w[j] = (__bf16)(f[r * 8 + j] * inv);
        *(bf16x8*)&p[(r * 64 + lane) * 8] = w;
    }
}

template<class CF>
__global__ __launch_bounds__(64)
void gemm1w(const __bf16* __restrict__ A, const __bf16* __restrict__ B,
            const float* __restrict__ bias,
            typename CF::OUT_T* __restrict__ C, typename CF::OUT_T* __restrict__ CT,
            int M, int N, int K)
{
    gemm_body<CF>(blockIdx.x, A, B, bias, C, CT, M, N, K);
}

template<class C1, class C2>
__global__ __launch_bounds__(64)
void gemm2w(int nblk1,
            const __bf16* __restrict__ A1, const __bf16* __restrict__ B1,
            const float* __restrict__ b1,
            typename C1::OUT_T* __restrict__ C1p, typename C1::OUT_T* __restrict__ CT1,
            int M1, int N1, int K1,
            const __bf16* __restrict__ A2, const __bf16* __restrict__ B2,
            const float* __restrict__ b2,
            typename C2::OUT_T* __restrict__ C2p, typename C2::OUT_T* __restrict__ CT2,
            int M2, int N2, int K2)
{
    const int b = blockIdx.x;
    if (b < nblk1)
        gemm_body<C1>(b, A1, B1, b1, C1p, CT1, M1, N1, K1);
    else
        gemm_body<C2>(b - nblk1, A2, B2, b2, C2p, CT2, M2, N2, K2);
}

template<class C1, class C2>
__global__ __launch_bounds__(64)
void gemm2smw(int nblk1, int nblk2,
              const __bf16* __restrict__ A1, const __bf16* __restrict__ B1,
              const float* __restrict__ b1, typename C1::OUT_T* __restrict__ C1p,
              int M1, int N1, int K1,
              const __bf16* __restrict__ A2, const __bf16* __restrict__ B2,
              const float* __restrict__ b2, typename C2::OUT_T* __restrict__ C2p,
              int M2, int N2, int K2,
              __bf16* __restrict__ SM)
{
    const int b = blockIdx.x;
    if (b < nblk1)
        gemm_body<C1>(b, A1, B1, b1, C1p, (typename C1::OUT_T*)nullptr, M1, N1, K1);
    else if (b < nblk1 + nblk2)
        gemm_body<C2>(b - nblk1, A2, B2, b2, C2p, (typename C2::OUT_T*)nullptr, M2, N2, K2);
    else
        softmax_row_w(SM + (size_t)(b - nblk1 - nblk2) * 2048);
}

__global__ __launch_bounds__(64)
void row_softmax_w(__bf16* __restrict__ A)
{
    softmax_row_w(A + (size_t)blockIdx.x * 2048);
}

// ---------------- prep (unchanged, 256-thread) ----------------
__device__ __forceinline__ void tp_tile(const float* __restrict__ in,
                                        __bf16* __restrict__ outp,
                                        int R, int C, int bx, int by)
{
    __shared__ float t[32][33];
    const int tx = threadIdx.x & 31, ty = threadIdx.x >> 5;
    #pragma unroll
    for (int i = ty; i < 32; i += 8)
        t[i][tx] = in[(size_t)(by + i) * C + (bx + tx)];
    __syncthreads();
    #pragma unroll
    for (int i = ty; i < 32; i += 8)
        outp[(size_t)(bx + i) * R + (by + tx)] = (__bf16)t[tx][i];
}

__device__ __forceinline__ void cast_blk(const float* __restrict__ s,
                                         __bf16* __restrict__ d, int blk)
{
    const int i = blk * 1024 + threadIdx.x * 4;
    float4 v = *(const float4*)&s[i];
    bf16x4 w = { (__bf16)v.x, (__bf16)v.y, (__bf16)v.z, (__bf16)v.w };
    *(bf16x4*)&d[i] = w;
}

__global__ __launch_bounds__(256)
void prep(const float* __restrict__ vc, __bf16* __restrict__ vcT,
          const float* __restrict__ vm, __bf16* __restrict__ vmT,
          const float* __restrict__ W_ak, __bf16* __restrict__ W_akb,
          const float* __restrict__ W_c, __bf16* __restrict__ W_cb,
          const float* __restrict__ W_mad, __bf16* __restrict__ W_madb,
          const float* __restrict__ W_gcn, __bf16* __restrict__ W_gcnT)
{
    const int x = blockIdx.x;
    if (blockIdx.z == 0) {
        const float* in = (x < 2048) ? vc : vm;
        __bf16* o       = (x < 2048) ? vcT : vmT;
        const int e = x & 2047;
        tp_tile(in, o, 1024, 2048, (e & 63) * 32, (e >> 6) * 32);
    } else if (blockIdx.z == 1) {
        if (x < 2048)      cast_blk(W_ak, W_akb, x);
        else if (x < 3072) cast_blk(W_c, W_cb, x - 2048);
        else               cast_blk(W_mad, W_madb, x - 3072);
    } else {
        if (x >= 1024) return;
        tp_tile(W_gcn, W_gcnT, 1024, 1024, (x & 31) * 32, (x >> 5) * 32);
    }
}

extern "C" void kernel_launch(void* const* d_in, const int* in_sizes, int n_in,
                              void* d_out, int out_size, void* d_ws, size_t ws_size,
                              hipStream_t stream)
{
    const float* vc    = (const float*)d_in[0];
    const float* vm    = (const float*)d_in[1];
    const float* W_ak  = (const float*)d_in[2];
    const float* b_ak  = (const float*)d_in[3];
    const float* W_c   = (const float*)d_in[4];
    const float* b_c   = (const float*)d_in[5];
    const float* W_mad = (const float*)d_in[6];
    const float* b_mad = (const float*)d_in[7];
    const float* W_gcn = (const float*)d_in[8];
    const float* b_gcn = (const float*)d_in[9];
    float* out = (float*)d_out;

    // Arena, 32 MB (same as r11/r12):
    char* ws = (char*)d_ws;
    const size_t MB = 1u << 20;
    __bf16* ST     = (__bf16*)(ws);
    __bf16* P      = (__bf16*)(ws);
    __bf16* vcT    = (__bf16*)(ws + 8 * MB);
    __bf16* vmaT   = (__bf16*)(ws + 8 * MB);
    __bf16* W_akb  = (__bf16*)(ws + 12 * MB);
    __bf16* vmm    = (__bf16*)(ws + 12 * MB);
    __bf16* vmT    = (__bf16*)(ws + 16 * MB);
    __bf16* xT     = (__bf16*)(ws + 16 * MB);
    __bf16* W_cb   = (__bf16*)(ws + 20 * MB);
    __bf16* W_madb = (__bf16*)(ws + 22 * MB);
    __bf16* vmrT   = (__bf16*)(ws + 24 * MB);
    __bf16* W_gcnT = (__bf16*)(ws + 28 * MB);

    //                 OUT    BIAS RELU  ST  PM  PN NPC   (nm x nn tiles)
    using G3  = GC<__bf16, 2, false, 0,  8, 16, 2>;   // 32x32, 1024 blk
    using G5  = GC<__bf16, 1, true,  1,  8,  8, 4>;   // 16x32,  512 blk
    using G6  = GC<__bf16, 0, false, 0,  8,  8, 4>;   // 16x32,  512 blk
    using G11 = GC<__bf16, 1, false, 0,  8,  8, 4>;   // 16x32,  512 blk
    using G7  = GC<__bf16, 2, false, 0,  8,  8, 2>;   // 32x16,  512 blk
    using G9  = GC<__bf16, 0, false, 0,  8, 16, 2>;   // 32x32, 1024 blk
    using G12 = GC<float,  0, false, 1,  8,  8, 2>;   // 32x16,  512 blk

    // L1. input casts/transposes
    prep<<<dim3(4096, 1, 3), 256, 0, stream>>>(vc, vcT, vm, vmT, W_ak, W_akb,
                                               W_c, W_cb, W_mad, W_madb,
                                               W_gcn, W_gcnT);
    // L2. [G3 1024 | G5 512]: ST = vcT*W_akb + b_ak (2048x2048 K1024)
    //                         vmrT = relu(W_cb*vmT + b_c)^T (1024x2048 K1024)
    gemm2w<G3, G5><<<1536, 64, 0, stream>>>(1024,
        vcT, W_akb, b_ak, ST, (__bf16*)nullptr, 2048, 2048, 1024,
        W_cb, vmT, b_c, (__bf16*)nullptr, vmrT, 1024, 2048, 1024);
    // L3. [G6 512 | G11 512 | smST 2048]: vmm = W_madb*vmrT (1024x2048 K1024)
    //     xT = W_gcnT*vmrT + b_gcn (1024x2048 K1024); row-softmax(ST)
    gemm2smw<G6, G11><<<3072, 64, 0, stream>>>(512, 512,
        W_madb, vmrT, nullptr, vmm, 1024, 2048, 1024,
        W_gcnT, vmrT, b_gcn, xT, 1024, 2048, 1024,
        ST);
    // L4. G7: vmaT = ST_sm*vmm + b_mad (2048x1024 K2048), 512 blk
    gemm1w<G7><<<512, 64, 0, stream>>>(ST, vmm, b_mad, vmaT, (__bf16*)nullptr,
                                       2048, 1024, 2048);
    // L5. G9: P = vmaT*vmaT^T (2048x2048 K1024), 1024 blk
    gemm1w<G9><<<1024, 64, 0, stream>>>(vmaT, vmaT, nullptr, P, (__bf16*)nullptr,
                                        2048, 2048, 1024);
    // L6. softmax rows of P
    row_softmax_w<<<2048, 64, 0, stream>>>(P);
    // L7. G12: out = (P*xT)^T direct fp32 (2048x1024 K2048), 512 blk
    gemm1w<G12><<<512, 64, 0, stream>>>(P, xT, nullptr, (float*)nullptr, out,
                                        2048, 1024, 2048);
}

// Round 14
// 244.530 us; speedup vs baseline: 1.1575x; 1.1575x over previous
//
#include <hip/hip_runtime.h>
#include <hip/hip_bf16.h>

// CHNN=1024, K=L=2048. Inputs fp32, output fp32. bf16 MFMA (16x16x32), fp32
// acc, TN layout. Round 14: revert to r12 GEMM core (LDS-DMA staging +
// vmcnt(8) pipelining -- r13 proved removing LDS regresses 36%). New:
// SPLIT-K2 on the two 2048^2 GEMMs (G3, G9) with the partial-sum reduction
// FUSED into the row-softmax passes that already follow them (bf16 partials,
// fp32 add; G3's bias also folded into the softmax). L2: 2560 blk, L5: 2048
// blk. d_ws is 256 MiB (fill WRITE_SIZE evidence) -> dedicated 72 MB arena,
// no buffer aliasing.

typedef __bf16 bf16x4 __attribute__((ext_vector_type(4)));
typedef __bf16 bf16x8 __attribute__((ext_vector_type(8)));
typedef float  f32x4  __attribute__((ext_vector_type(4)));

typedef const void __attribute__((address_space(1)))* gptr_t;
typedef void       __attribute__((address_space(3)))* lptr_t;

__device__ __forceinline__ void load16_lds(const __bf16* g, __bf16* l)
{
    __builtin_amdgcn_global_load_lds((gptr_t)g, (lptr_t)l, 16, 0, 0);
}

#define WAITCNT_VM8 0x0F78   // vmcnt(8)
#define WAITCNT_VM0 0x0F70   // vmcnt(0)

template<typename OT, int BIAS_, bool RELU_, int STORE_>
struct GC {
    using OUT_T = OT;
    static constexpr int BIAS = BIAS_, STORE = STORE_;
    static constexpr bool RELU = RELU_;
};

// Single-wave 64x64 TN GEMM (r12 core + KLEN/LDK split-K support).
// C(M,N) = A(M,:)*B(N,:)^T over KLEN k's; LDK = row stride of A and B.
// BIAS: 0 none, 1 bias[row], 2 bias[col]. STORE: 0 C[m][n], 1 CT[n][m].
template<class CF>
__device__ __forceinline__ void gemm_body(
    int bid, __bf16* sA, __bf16* sB,
    const __bf16* __restrict__ A, const __bf16* __restrict__ B,
    const float* __restrict__ bias,
    typename CF::OUT_T* __restrict__ C, typename CF::OUT_T* __restrict__ CT,
    int M, int N, int KLEN, int LDK, int ntx)
{
    const int lane = threadIdx.x & 63;
    const int m0 = (bid / ntx) * 64, n0 = (bid % ntx) * 64;
    const __bf16* gA = A + (size_t)m0 * LDK;
    const __bf16* gB = B + (size_t)n0 * LDK;

    f32x4 acc[4][4];
    #pragma unroll
    for (int i = 0; i < 4; ++i)
        #pragma unroll
        for (int j = 0; j < 4; ++j)
            acc[i][j] = (f32x4){0.f, 0.f, 0.f, 0.f};

    auto stage = [&](int k0, int buf) {
        #pragma unroll
        for (int i = 0; i < 4; ++i) {
            const int c = i * 64 + lane;
            load16_lds(gA + (size_t)(c >> 2) * LDK + k0 + (c & 3) * 8,
                       &sA[buf * 2048 + i * 512]);
        }
        #pragma unroll
        for (int i = 0; i < 4; ++i) {
            const int c = i * 64 + lane;
            load16_lds(gB + (size_t)(c >> 2) * LDK + k0 + (c & 3) * 8,
                       &sB[buf * 2048 + i * 512]);
        }
    };

    stage(0, 0);
    stage(32, 1);
    int cur = 0;
    for (int k0 = 0; k0 < KLEN - 32; k0 += 32) {
        __builtin_amdgcn_s_waitcnt(WAITCNT_VM8);
        bf16x8 af[4], bfr[4];
        #pragma unroll
        for (int i = 0; i < 4; ++i) {
            af[i]  = *(const bf16x8*)&sA[cur * 2048 + (i * 16 + (lane & 15)) * 32 + (lane >> 4) * 8];
            bfr[i] = *(const bf16x8*)&sB[cur * 2048 + (i * 16 + (lane & 15)) * 32 + (lane >> 4) * 8];
        }
        #pragma unroll
        for (int i = 0; i < 4; ++i)
            #pragma unroll
            for (int j = 0; j < 4; ++j)
                acc[i][j] = __builtin_amdgcn_mfma_f32_16x16x32_bf16(af[i], bfr[j], acc[i][j], 0, 0, 0);
        if (k0 + 64 < KLEN) stage(k0 + 64, cur);
        cur ^= 1;
    }
    __builtin_amdgcn_s_waitcnt(WAITCNT_VM0);
    {
        bf16x8 af[4], bfr[4];
        #pragma unroll
        for (int i = 0; i < 4; ++i) {
            af[i]  = *(const bf16x8*)&sA[cur * 2048 + (i * 16 + (lane & 15)) * 32 + (lane >> 4) * 8];
            bfr[i] = *(const bf16x8*)&sB[cur * 2048 + (i * 16 + (lane & 15)) * 32 + (lane >> 4) * 8];
        }
        #pragma unroll
        for (int i = 0; i < 4; ++i)
            #pragma unroll
            for (int j = 0; j < 4; ++j)
                acc[i][j] = __builtin_amdgcn_mfma_f32_16x16x32_bf16(af[i], bfr[j], acc[i][j], 0, 0, 0);
    }

    // Epilogue. C/D layout: col=lane&15, row=(lane>>4)*4+reg (verified r6-r13).
    #pragma unroll
    for (int i = 0; i < 4; ++i) {
        const int rowb = m0 + i * 16 + (lane >> 4) * 4;
        #pragma unroll
        for (int j = 0; j < 4; ++j) {
            const int col = n0 + j * 16 + (lane & 15);
            f32x4 v = acc[i][j];
            #pragma unroll
            for (int r = 0; r < 4; ++r) {
                float f = v[r];
                if (CF::BIAS == 1) f += bias[rowb + r];
                if (CF::BIAS == 2) f += bias[col];
                if (CF::RELU) f = fmaxf(f, 0.f);
                v[r] = f;
            }
            if (CF::STORE == 0) {
                #pragma unroll
                for (int r = 0; r < 4; ++r)
                    C[(size_t)(rowb + r) * N + col] = (typename CF::OUT_T)v[r];
            } else {
                if constexpr (sizeof(typename CF::OUT_T) == 4) {
                    *(f32x4*)&CT[(size_t)col * M + rowb] = v;
                } else {
                    bf16x4 w = { (__bf16)v[0], (__bf16)v[1], (__bf16)v[2], (__bf16)v[3] };
                    *(bf16x4*)&CT[(size_t)col * M + rowb] = w;
                }
            }
        }
    }
}

// Single-wave row softmax over p0+p1 (+optional bias), result -> p0 (bf16).
__device__ __forceinline__ void softmax_row2(__bf16* __restrict__ p0,
                                             const __bf16* __restrict__ p1,
                                             const float* __restrict__ bias)
{
    const int lane = threadIdx.x & 63;
    float f[32];
    float m = -1e30f;
    #pragma unroll
    for (int r = 0; r < 4; ++r) {
        const int base = (r * 64 + lane) * 8;
        bf16x8 a = *(const bf16x8*)&p0[base];
        bf16x8 b = *(const bf16x8*)&p1[base];
        #pragma unroll
        for (int j = 0; j < 8; ++j) {
            float x = (float)a[j] + (float)b[j];
            if (bias) x += bias[base + j];
            f[r * 8 + j] = x;
            m = fmaxf(m, x);
        }
    }
    #pragma unroll
    for (int s = 1; s < 64; s <<= 1) m = fmaxf(m, __shfl_xor(m, s, 64));
    float sum = 0.f;
    #pragma unroll
    for (int i = 0; i < 32; ++i) { f[i] = expf(f[i] - m); sum += f[i]; }
    #pragma unroll
    for (int s = 1; s < 64; s <<= 1) sum += __shfl_xor(sum, s, 64);
    const float inv = 1.f / sum;
    #pragma unroll
    for (int r = 0; r < 4; ++r) {
        bf16x8 w;
        #pragma unroll
        for (int j = 0; j < 8; ++j) w[j] = (__bf16)(f[r * 8 + j] * inv);
        *(bf16x8*)&p0[(r * 64 + lane) * 8] = w;
    }
}

using G3c  = GC<__bf16, 0, false, 0>;   // split-K partials, bias in softmax
using G5c  = GC<__bf16, 1, true,  1>;
using G11c = GC<__bf16, 1, false, 0>;
using G7c  = GC<__bf16, 2, false, 0>;
using G12c = GC<float,  0, false, 1>;

// L2: [G3 half0 1024 | G3 half1 1024 | G5 512] = 2560 blocks
__global__ __launch_bounds__(64)
void k_L2(const __bf16* __restrict__ vcT, const __bf16* __restrict__ W_akb,
          __bf16* __restrict__ ST0, __bf16* __restrict__ ST1,
          const __bf16* __restrict__ W_cb, const __bf16* __restrict__ vmT,
          const float* __restrict__ b_c, __bf16* __restrict__ vmrT)
{
    __shared__ __bf16 s[8192];
    const int b = blockIdx.x;
    if (b < 1024)
        gemm_body<G3c>(b, s, s + 4096, vcT, W_akb, nullptr, ST0, (__bf16*)nullptr,
                       2048, 2048, 512, 1024, 32);
    else if (b < 2048)
        gemm_body<G3c>(b - 1024, s, s + 4096, vcT + 512, W_akb + 512, nullptr, ST1,
                       (__bf16*)nullptr, 2048, 2048, 512, 1024, 32);
    else
        gemm_body<G5c>(b - 2048, s, s + 4096, W_cb, vmT, b_c, (__bf16*)nullptr,
                       vmrT, 1024, 2048, 1024, 1024, 32);
}

// L3: [G6 512 | G11 512 | softmax2(ST) 2048] = 3072 blocks
__global__ __launch_bounds__(64)
void k_L3(const __bf16* __restrict__ W_madb, const __bf16* __restrict__ vmrT,
          __bf16* __restrict__ vmm,
          const __bf16* __restrict__ W_gcnT, const float* __restrict__ b_gcn,
          __bf16* __restrict__ xT,
          __bf16* __restrict__ ST0, const __bf16* __restrict__ ST1,
          const float* __restrict__ b_ak)
{
    __shared__ __bf16 s[8192];
    const int b = blockIdx.x;
    if (b < 512)
        gemm_body<G3c>(b, s, s + 4096, W_madb, vmrT, nullptr, vmm, (__bf16*)nullptr,
                       1024, 2048, 1024, 1024, 32);
    else if (b < 1024)
        gemm_body<G11c>(b - 512, s, s + 4096, W_gcnT, vmrT, b_gcn, xT,
                        (__bf16*)nullptr, 1024, 2048, 1024, 1024, 32);
    else {
        const size_t row = b - 1024;
        softmax_row2(ST0 + row * 2048, ST1 + row * 2048, b_ak);
    }
}

// L4: G7 = ST_sm*vmm + b_mad (2048x1024, K=2048), 512 blocks
__global__ __launch_bounds__(64)
void k_L4(const __bf16* __restrict__ ST, const __bf16* __restrict__ vmm,
          const float* __restrict__ b_mad, __bf16* __restrict__ vmaT)
{
    __shared__ __bf16 s[8192];
    gemm_body<G7c>(blockIdx.x, s, s + 4096, ST, vmm, b_mad, vmaT,
                   (__bf16*)nullptr, 2048, 1024, 2048, 2048, 16);
}

// L5: G9 split-K2 = vmaT*vmaT^T partials (2048x2048), 2048 blocks
__global__ __launch_bounds__(64)
void k_L5(const __bf16* __restrict__ vmaT, __bf16* __restrict__ P0,
          __bf16* __restrict__ P1)
{
    __shared__ __bf16 s[8192];
    const int b = blockIdx.x;
    if (b < 1024)
        gemm_body<G3c>(b, s, s + 4096, vmaT, vmaT, nullptr, P0, (__bf16*)nullptr,
                       2048, 2048, 512, 1024, 32);
    else
        gemm_body<G3c>(b - 1024, s, s + 4096, vmaT + 512, vmaT + 512, nullptr, P1,
                       (__bf16*)nullptr, 2048, 2048, 512, 1024, 32);
}

// L6: softmax2(P), 2048 blocks
__global__ __launch_bounds__(64)
void k_L6(__bf16* __restrict__ P0, const __bf16* __restrict__ P1)
{
    const size_t row = blockIdx.x;
    softmax_row2(P0 + row * 2048, P1 + row * 2048, nullptr);
}

// L7: G12 = (P_sm*xT)^T -> out fp32 (2048x1024, K=2048), 512 blocks
__global__ __launch_bounds__(64)
void k_L7(const __bf16* __restrict__ P, const __bf16* __restrict__ xT,
          float* __restrict__ out)
{
    __shared__ __bf16 s[8192];
    gemm_body<G12c>(blockIdx.x, s, s + 4096, P, xT, nullptr, (float*)nullptr,
                    out, 2048, 1024, 2048, 2048, 16);
}

// ---------------- prep (unchanged from r12) ----------------
__device__ __forceinline__ void tp_tile(const float* __restrict__ in,
                                        __bf16* __restrict__ outp,
                                        int R, int C, int bx, int by)
{
    __shared__ float t[32][33];
    const int tx = threadIdx.x & 31, ty = threadIdx.x >> 5;
    #pragma unroll
    for (int i = ty; i < 32; i += 8)
        t[i][tx] = in[(size_t)(by + i) * C + (bx + tx)];
    __syncthreads();
    #pragma unroll
    for (int i = ty; i < 32; i += 8)
        outp[(size_t)(bx + i) * R + (by + tx)] = (__bf16)t[tx][i];
}

__device__ __forceinline__ void cast_blk(const float* __restrict__ s,
                                         __bf16* __restrict__ d, int blk)
{
    const int i = blk * 1024 + threadIdx.x * 4;
    float4 v = *(const float4*)&s[i];
    bf16x4 w = { (__bf16)v.x, (__bf16)v.y, (__bf16)v.z, (__bf16)v.w };
    *(bf16x4*)&d[i] = w;
}

__global__ __launch_bounds__(256)
void prep(const float* __restrict__ vc, __bf16* __restrict__ vcT,
          const float* __restrict__ vm, __bf16* __restrict__ vmT,
          const float* __restrict__ W_ak, __bf16* __restrict__ W_akb,
          const float* __restrict__ W_c, __bf16* __restrict__ W_cb,
          const float* __restrict__ W_mad, __bf16* __restrict__ W_madb,
          const float* __restrict__ W_gcn, __bf16* __restrict__ W_gcnT)
{
    const int x = blockIdx.x;
    if (blockIdx.z == 0) {
        const float* in = (x < 2048) ? vc : vm;
        __bf16* o       = (x < 2048) ? vcT : vmT;
        const int e = x & 2047;
        tp_tile(in, o, 1024, 2048, (e & 63) * 32, (e >> 6) * 32);
    } else if (blockIdx.z == 1) {
        if (x < 2048)      cast_blk(W_ak, W_akb, x);
        else if (x < 3072) cast_blk(W_c, W_cb, x - 2048);
        else               cast_blk(W_mad, W_madb, x - 3072);
    } else {
        if (x >= 1024) return;
        tp_tile(W_gcn, W_gcnT, 1024, 1024, (x & 31) * 32, (x >> 5) * 32);
    }
}

extern "C" void kernel_launch(void* const* d_in, const int* in_sizes, int n_in,
                              void* d_out, int out_size, void* d_ws, size_t ws_size,
                              hipStream_t stream)
{
    const float* vc    = (const float*)d_in[0];
    const float* vm    = (const float*)d_in[1];
    const float* W_ak  = (const float*)d_in[2];
    const float* b_ak  = (const float*)d_in[3];
    const float* W_c   = (const float*)d_in[4];
    const float* b_c   = (const float*)d_in[5];
    const float* W_mad = (const float*)d_in[6];
    const float* b_mad = (const float*)d_in[7];
    const float* W_gcn = (const float*)d_in[8];
    const float* b_gcn = (const float*)d_in[9];
    float* out = (float*)d_out;

    // Arena: 72 MB of the 256 MiB d_ws, zero aliasing.
    char* ws = (char*)d_ws;
    const size_t MB = 1u << 20;
    __bf16* vcT    = (__bf16*)(ws);            // 4 MB
    __bf16* vmT    = (__bf16*)(ws + 4 * MB);   // 4 MB
    __bf16* W_akb  = (__bf16*)(ws + 8 * MB);   // 4 MB
    __bf16* W_cb   = (__bf16*)(ws + 12 * MB);  // 2 MB
    __bf16* W_madb = (__bf16*)(ws + 14 * MB);  // 2 MB
    __bf16* W_gcnT = (__bf16*)(ws + 16 * MB);  // 2 MB
    __bf16* vmrT   = (__bf16*)(ws + 18 * MB);  // 4 MB
    __bf16* ST0    = (__bf16*)(ws + 24 * MB);  // 8 MB (becomes final ST)
    __bf16* ST1    = (__bf16*)(ws + 32 * MB);  // 8 MB
    __bf16* vmm    = (__bf16*)(ws + 40 * MB);  // 4 MB
    __bf16* xT     = (__bf16*)(ws + 44 * MB);  // 4 MB
    __bf16* vmaT   = (__bf16*)(ws + 48 * MB);  // 4 MB
    __bf16* P0     = (__bf16*)(ws + 56 * MB);  // 8 MB (becomes final P)
    __bf16* P1     = (__bf16*)(ws + 64 * MB);  // 8 MB

    // L1. input casts/transposes
    prep<<<dim3(4096, 1, 3), 256, 0, stream>>>(vc, vcT, vm, vmT, W_ak, W_akb,
                                               W_c, W_cb, W_mad, W_madb,
                                               W_gcn, W_gcnT);
    // L2. G3 split-K2 (2048) + G5 (512) = 2560 blocks (10/CU)
    k_L2<<<2560, 64, 0, stream>>>(vcT, W_akb, ST0, ST1, W_cb, vmT, b_c, vmrT);
    // L3. G6 (512) + G11 (512) + softmax2(ST)+bias (2048) = 3072 blocks
    k_L3<<<3072, 64, 0, stream>>>(W_madb, vmrT, vmm, W_gcnT, b_gcn, xT,
                                  ST0, ST1, b_ak);
    // L4. G7 = ST_sm*vmm + b_mad (512 blocks)
    k_L4<<<512, 64, 0, stream>>>(ST0, vmm, b_mad, vmaT);
    // L5. G9 split-K2 partials (2048 blocks, 8/CU)
    k_L5<<<2048, 64, 0, stream>>>(vmaT, P0, P1);
    // L6. softmax2(P) (2048 blocks)
    k_L6<<<2048, 64, 0, stream>>>(P0, P1);
    // L7. G12 -> out fp32 (512 blocks)
    k_L7<<<512, 64, 0, stream>>>(P0, xT, out);
}